// Round 1
// baseline (382.472 us; speedup 1.0000x reference)
//
#include <hip/hip_runtime.h>

// Problem constants (match reference):
//   attrs:    [8, 10000, 3, 16] fp32   (flat face table of 80000 faces x 48 floats)
//   baryw:    [8, 512, 512, 3]  fp32
//   triangle: [8, 512, 512]     int32  (-1 = background; indexes flat [BZ*NF])
//   out:      [8, 17, 512, 512] fp32   (16 interpolated channels + visibility)
constexpr int BZ = 8, NF = 10000, D = 16, HImg = 512, WImg = 512;
constexpr int HW = HImg * WImg;          // 262144
constexpr int NPIX = BZ * HW;            // 2097152
constexpr int PIX_PER_THREAD = 4;
constexpr int NTHREADS = NPIX / PIX_PER_THREAD;  // 524288
constexpr int BLOCK = 256;

__global__ __launch_bounds__(BLOCK) void renderer_kernel(
    const float* __restrict__ attrs,
    const float* __restrict__ baryw,
    const int*   __restrict__ tri,
    float*       __restrict__ out)
{
    const int tid = blockIdx.x * BLOCK + threadIdx.x;
    const int p0  = tid * PIX_PER_THREAD;          // first pixel (flat over BZ*H*W)
    if (p0 >= NPIX) return;

    const int n   = p0 / HW;                       // image index (4 | HW, so all 4 pixels same n)
    const int pix = p0 - n * HW;                   // pixel within image

    // --- coalesced vector loads ---
    const int4 t4 = *reinterpret_cast<const int4*>(tri + p0);        // 4 triangle ids
    const float4* bw = reinterpret_cast<const float4*>(baryw + (size_t)p0 * 3);
    const float4 b0 = bw[0], b1 = bw[1], b2 = bw[2];                 // 12 weights

    // weights per pixel j (w[j][k]); branchless background: zero the weights
    float w[PIX_PER_THREAD][3] = {
        {b0.x, b0.y, b0.z},
        {b0.w, b1.x, b1.y},
        {b1.z, b1.w, b2.x},
        {b2.y, b2.z, b2.w},
    };
    const int t[PIX_PER_THREAD] = {t4.x, t4.y, t4.z, t4.w};

    float vis[PIX_PER_THREAD];
    const float4* abase[PIX_PER_THREAD];
#pragma unroll
    for (int j = 0; j < PIX_PER_THREAD; ++j) {
        const bool bg = (t[j] < 0);
        vis[j] = bg ? 0.0f : 1.0f;
        const int tc = bg ? 0 : t[j];              // clamp; weights zeroed below
        abase[j] = reinterpret_cast<const float4*>(attrs + (size_t)tc * (3 * D));
        w[j][0] *= vis[j];
        w[j][1] *= vis[j];
        w[j][2] *= vis[j];
    }

    const size_t outbase = (size_t)n * (D + 1) * HW + pix;

    // Process 4 channels (one float4 of the face record) at a time to bound
    // register pressure: per chunk we hold 4 pixels x 4 channels = 16 floats
    // of results plus 3 float4 gather temps.
#pragma unroll
    for (int c = 0; c < 4; ++c) {
        float r[PIX_PER_THREAD][4];
#pragma unroll
        for (int j = 0; j < PIX_PER_THREAD; ++j) {
            // face record layout: [k=0: d0..15][k=1: d0..15][k=2: d0..15]
            const float4 a0 = abase[j][c];         // k=0, channels 4c..4c+3
            const float4 a1 = abase[j][4 + c];     // k=1
            const float4 a2 = abase[j][8 + c];     // k=2
            r[j][0] = w[j][0] * a0.x + w[j][1] * a1.x + w[j][2] * a2.x;
            r[j][1] = w[j][0] * a0.y + w[j][1] * a1.y + w[j][2] * a2.y;
            r[j][2] = w[j][0] * a0.z + w[j][1] * a1.z + w[j][2] * a2.z;
            r[j][3] = w[j][0] * a0.w + w[j][1] * a1.w + w[j][2] * a2.w;
        }
        // transpose: one float4 store per channel = 4 consecutive pixels
#pragma unroll
        for (int i = 0; i < 4; ++i) {
            const int d = c * 4 + i;
            float4 o;
            o.x = r[0][i]; o.y = r[1][i]; o.z = r[2][i]; o.w = r[3][i];
            *reinterpret_cast<float4*>(out + outbase + (size_t)d * HW) = o;
        }
    }

    // visibility channel
    float4 v;
    v.x = vis[0]; v.y = vis[1]; v.z = vis[2]; v.w = vis[3];
    *reinterpret_cast<float4*>(out + outbase + (size_t)D * HW) = v;
}

extern "C" void kernel_launch(void* const* d_in, const int* in_sizes, int n_in,
                              void* d_out, int out_size, void* d_ws, size_t ws_size,
                              hipStream_t stream) {
    const float* attrs = (const float*)d_in[0];
    const float* baryw = (const float*)d_in[1];
    const int*   tri   = (const int*)d_in[2];
    float*       out   = (float*)d_out;

    const int grid = NTHREADS / BLOCK;  // 2048 blocks
    renderer_kernel<<<grid, BLOCK, 0, stream>>>(attrs, baryw, tri, out);
}

// Round 2
// 227.961 us; speedup vs baseline: 1.6778x; 1.6778x over previous
//
#include <hip/hip_runtime.h>
#include <hip/hip_fp16.h>

// Problem constants (match reference):
//   attrs:    [8, 10000, 3, 16] fp32   (flat face table of 80000 faces x 48 floats)
//   baryw:    [8, 512, 512, 3]  fp32
//   triangle: [8, 512, 512]     int32  (-1 = background; indexes flat [BZ*NF])
//   out:      [8, 17, 512, 512] fp32   (16 interpolated channels + visibility)
//
// Strategy (R2): the bottleneck is random-gather traffic (FETCH 823 MB vs
// 139 MB writes). Pre-convert the face table to fp16 padded to one 128 B
// L2 line per face (10.24 MB in d_ws). Each pixel then misses at most ONE
// line instead of ~3, and the table gets a ~40% L2 hit rate.
constexpr int BZ = 8, NF = 10000, D = 16, HImg = 512, WImg = 512;
constexpr int HW = HImg * WImg;          // 262144
constexpr int NPIX = BZ * HW;            // 2097152
constexpr int NFACES = BZ * NF;          // 80000
constexpr int PIX_PER_THREAD = 4;
constexpr int NTHREADS = NPIX / PIX_PER_THREAD;  // 524288
constexpr int BLOCK = 256;
// fp16 record: 3 vertices x 16 ch x 2 B = 96 B, padded to 128 B (one line).
constexpr size_t REC_USHORTS = 64;       // 128 B / 2
constexpr size_t WS_NEEDED = (size_t)NFACES * 128;

// ---- pass 1: fp32 attrs -> fp16 padded records --------------------------
// 6 chunks of 8 values per face; source offset face*48 + c*8 (linear),
// dest offset face*64 + c*8 (pad lives at the tail of each record).
__global__ __launch_bounds__(BLOCK) void convert_kernel(
    const float* __restrict__ attrs, ushort* __restrict__ rec)
{
    const int tid = blockIdx.x * BLOCK + threadIdx.x;
    if (tid >= NFACES * 6) return;
    const int face = tid / 6;
    const int c    = tid - face * 6;
    const float4* src = reinterpret_cast<const float4*>(
        attrs + (size_t)face * 48 + c * 8);
    const float4 a = src[0], b = src[1];
    __half h[8];
    h[0] = __float2half_rn(a.x); h[1] = __float2half_rn(a.y);
    h[2] = __float2half_rn(a.z); h[3] = __float2half_rn(a.w);
    h[4] = __float2half_rn(b.x); h[5] = __float2half_rn(b.y);
    h[6] = __float2half_rn(b.z); h[7] = __float2half_rn(b.w);
    *reinterpret_cast<int4*>(rec + (size_t)face * REC_USHORTS + c * 8) =
        *reinterpret_cast<const int4*>(h);
}

__device__ inline void h8_to_f8(int4 raw, float f[8]) {
    const __half2* hp = reinterpret_cast<const __half2*>(&raw);
#pragma unroll
    for (int q = 0; q < 4; ++q) {
        const float2 t = __half22float2(hp[q]);
        f[2 * q]     = t.x;
        f[2 * q + 1] = t.y;
    }
}

// ---- pass 2: render from fp16 records -----------------------------------
__global__ __launch_bounds__(BLOCK) void render_f16_kernel(
    const ushort* __restrict__ rec,
    const float*  __restrict__ baryw,
    const int*    __restrict__ tri,
    float*        __restrict__ out)
{
    const int tid = blockIdx.x * BLOCK + threadIdx.x;
    const int p0  = tid * PIX_PER_THREAD;
    if (p0 >= NPIX) return;

    const int n   = p0 / HW;
    const int pix = p0 - n * HW;

    const int4 t4 = *reinterpret_cast<const int4*>(tri + p0);
    const float4* bw = reinterpret_cast<const float4*>(baryw + (size_t)p0 * 3);
    const float4 b0 = bw[0], b1 = bw[1], b2 = bw[2];

    float w[PIX_PER_THREAD][3] = {
        {b0.x, b0.y, b0.z},
        {b0.w, b1.x, b1.y},
        {b1.z, b1.w, b2.x},
        {b2.y, b2.z, b2.w},
    };
    const int t[PIX_PER_THREAD] = {t4.x, t4.y, t4.z, t4.w};

    float vis[PIX_PER_THREAD];
    const int4* rbase[PIX_PER_THREAD];
#pragma unroll
    for (int j = 0; j < PIX_PER_THREAD; ++j) {
        const bool bg = (t[j] < 0);
        vis[j] = bg ? 0.0f : 1.0f;
        const int tc = bg ? 0 : t[j];
        // record = 8 int4 (128 B): vertex k occupies int4 slots [2k, 2k+1]
        rbase[j] = reinterpret_cast<const int4*>(rec) + (size_t)tc * 8;
        w[j][0] *= vis[j];
        w[j][1] *= vis[j];
        w[j][2] *= vis[j];
    }

    const size_t outbase = (size_t)n * (D + 1) * HW + pix;

    // two chunks of 8 channels; per pixel per chunk: 3 x int4 (8 fp16 each)
#pragma unroll
    for (int c = 0; c < 2; ++c) {
        float r[PIX_PER_THREAD][8];
#pragma unroll
        for (int j = 0; j < PIX_PER_THREAD; ++j) {
            const int4 A0 = rbase[j][0 + c];   // vertex 0, chans 8c..8c+7
            const int4 A1 = rbase[j][2 + c];   // vertex 1
            const int4 A2 = rbase[j][4 + c];   // vertex 2
            float a0[8], a1[8], a2[8];
            h8_to_f8(A0, a0);
            h8_to_f8(A1, a1);
            h8_to_f8(A2, a2);
#pragma unroll
            for (int i = 0; i < 8; ++i)
                r[j][i] = w[j][0] * a0[i] + w[j][1] * a1[i] + w[j][2] * a2[i];
        }
#pragma unroll
        for (int i = 0; i < 8; ++i) {
            const int d = c * 8 + i;
            float4 o;
            o.x = r[0][i]; o.y = r[1][i]; o.z = r[2][i]; o.w = r[3][i];
            *reinterpret_cast<float4*>(out + outbase + (size_t)d * HW) = o;
        }
    }

    float4 v;
    v.x = vis[0]; v.y = vis[1]; v.z = vis[2]; v.w = vis[3];
    *reinterpret_cast<float4*>(out + outbase + (size_t)D * HW) = v;
}

// ---- fallback: direct fp32 path (R1 kernel) -----------------------------
__global__ __launch_bounds__(BLOCK) void renderer_f32_kernel(
    const float* __restrict__ attrs,
    const float* __restrict__ baryw,
    const int*   __restrict__ tri,
    float*       __restrict__ out)
{
    const int tid = blockIdx.x * BLOCK + threadIdx.x;
    const int p0  = tid * PIX_PER_THREAD;
    if (p0 >= NPIX) return;

    const int n   = p0 / HW;
    const int pix = p0 - n * HW;

    const int4 t4 = *reinterpret_cast<const int4*>(tri + p0);
    const float4* bw = reinterpret_cast<const float4*>(baryw + (size_t)p0 * 3);
    const float4 b0 = bw[0], b1 = bw[1], b2 = bw[2];

    float w[PIX_PER_THREAD][3] = {
        {b0.x, b0.y, b0.z},
        {b0.w, b1.x, b1.y},
        {b1.z, b1.w, b2.x},
        {b2.y, b2.z, b2.w},
    };
    const int t[PIX_PER_THREAD] = {t4.x, t4.y, t4.z, t4.w};

    float vis[PIX_PER_THREAD];
    const float4* abase[PIX_PER_THREAD];
#pragma unroll
    for (int j = 0; j < PIX_PER_THREAD; ++j) {
        const bool bg = (t[j] < 0);
        vis[j] = bg ? 0.0f : 1.0f;
        const int tc = bg ? 0 : t[j];
        abase[j] = reinterpret_cast<const float4*>(attrs + (size_t)tc * (3 * D));
        w[j][0] *= vis[j];
        w[j][1] *= vis[j];
        w[j][2] *= vis[j];
    }

    const size_t outbase = (size_t)n * (D + 1) * HW + pix;

#pragma unroll
    for (int c = 0; c < 4; ++c) {
        float r[PIX_PER_THREAD][4];
#pragma unroll
        for (int j = 0; j < PIX_PER_THREAD; ++j) {
            const float4 a0 = abase[j][c];
            const float4 a1 = abase[j][4 + c];
            const float4 a2 = abase[j][8 + c];
            r[j][0] = w[j][0] * a0.x + w[j][1] * a1.x + w[j][2] * a2.x;
            r[j][1] = w[j][0] * a0.y + w[j][1] * a1.y + w[j][2] * a2.y;
            r[j][2] = w[j][0] * a0.z + w[j][1] * a1.z + w[j][2] * a2.z;
            r[j][3] = w[j][0] * a0.w + w[j][1] * a1.w + w[j][2] * a2.w;
        }
#pragma unroll
        for (int i = 0; i < 4; ++i) {
            const int d = c * 4 + i;
            float4 o;
            o.x = r[0][i]; o.y = r[1][i]; o.z = r[2][i]; o.w = r[3][i];
            *reinterpret_cast<float4*>(out + outbase + (size_t)d * HW) = o;
        }
    }

    float4 v;
    v.x = vis[0]; v.y = vis[1]; v.z = vis[2]; v.w = vis[3];
    *reinterpret_cast<float4*>(out + outbase + (size_t)D * HW) = v;
}

extern "C" void kernel_launch(void* const* d_in, const int* in_sizes, int n_in,
                              void* d_out, int out_size, void* d_ws, size_t ws_size,
                              hipStream_t stream) {
    const float* attrs = (const float*)d_in[0];
    const float* baryw = (const float*)d_in[1];
    const int*   tri   = (const int*)d_in[2];
    float*       out   = (float*)d_out;

    const int grid = NTHREADS / BLOCK;  // 2048 blocks

    if (ws_size >= WS_NEEDED) {
        ushort* rec = (ushort*)d_ws;
        const int conv_grid = (NFACES * 6 + BLOCK - 1) / BLOCK;  // 1875
        convert_kernel<<<conv_grid, BLOCK, 0, stream>>>(attrs, rec);
        render_f16_kernel<<<grid, BLOCK, 0, stream>>>(rec, baryw, tri, out);
    } else {
        renderer_f32_kernel<<<grid, BLOCK, 0, stream>>>(attrs, baryw, tri, out);
    }
}